// Round 6
// baseline (433.467 us; speedup 1.0000x reference)
//
#include <hip/hip_runtime.h>
#include <cstdint>

// Problem constants (fixed shapes)
#define E_DIM   576
#define HEADS   18
#define NPTS    12
#define DDEPTH  5
#define HDIM    32
#define BSZ     2
#define GH      64
#define GW      80
#define NQ      (GH*GW)       // 5120
#define NTOK    (NQ*DDEPTH)   // 25600
#define MIXW    864           // 648 offsets + 216 attn logits
#define BQ_TOT  (BSZ*NQ)      // 10240

typedef __attribute__((ext_vector_type(8))) short short8;
typedef __attribute__((ext_vector_type(4))) float f32x4;
typedef __attribute__((ext_vector_type(4))) uint32_t u32x4;

__device__ __forceinline__ float b2f_lo(uint32_t u) {
    union { uint32_t u; float f; } v; v.u = u << 16; return v.f;
}
__device__ __forceinline__ float b2f_hi(uint32_t u) {
    union { uint32_t u; float f; } v; v.u = u & 0xffff0000u; return v.f;
}
__device__ __forceinline__ ushort f2b(float f) {
    union { float f; uint32_t u; } v; v.f = f;
    return (ushort)((v.u + 0x7fffu + ((v.u >> 16) & 1u)) >> 16);
}

// ---------------------------------------------------------------------------
// Weight prep only (value/query casts are fused into the GEMM A-staging now):
// weight transposes + bias concat, ~2.7 MB total.
__global__ void prep_weights(const float* __restrict__ W_v, const float* __restrict__ W_out,
                             const float* __restrict__ W_off, const float* __restrict__ W_attn,
                             const float* __restrict__ b_off, const float* __restrict__ b_attn,
                             ushort* __restrict__ wt_v, ushort* __restrict__ wt_out,
                             ushort* __restrict__ wt_mix, float* __restrict__ bias_mix) {
    int idx = blockIdx.x * blockDim.x + threadIdx.x;
    if (idx < 864) bias_mix[idx] = (idx < 648) ? b_off[idx] : b_attn[idx - 648];
    if (idx < 331776) {
        int n = idx / E_DIM, k = idx - n * E_DIM;
        wt_v[idx] = f2b(W_v[(size_t)k * E_DIM + n]);
    } else if (idx < 663552) {
        int j = idx - 331776;
        int n = j / E_DIM, k = j - n * E_DIM;
        wt_out[j] = f2b(W_out[(size_t)k * E_DIM + n]);
    } else if (idx < 1161216) {
        int j = idx - 663552;
        int n = j / E_DIM, k = j - n * E_DIM;
        float v = (n < 648) ? W_off[(size_t)k * 648 + n] : W_attn[(size_t)k * 216 + (n - 648)];
        wt_mix[j] = f2b(v);
    }
}

// ---------------------------------------------------------------------------
// MFMA GEMM body: C[M,N] = A[M,K] @ Bt[N,K]^T + bias[N]
// Tile 128x96, BK=32, 256 threads = 4 waves in a 2x2 grid (each wave 64x48).
// Round-1/5 proven structure: single-buffered, XOR k-slot swizzle
// (phys_slot = logical ^ ((row>>1)&3)), XCD-chunked block map (round 5:
// FETCH 164->44 MB — panel sharers MUST be XCD-colocated).
//
// A-operand modes (fp32->bf16 cast fused into staging; identical f2b math):
//   AM_BF16  : A bf16 in HBM, staged via global_load_lds
//   AM_F32   : A fp32; reg-staged (4x dwordx4 -> f2b pack -> 2x ds_write_b128)
//   AM_F32ADD: two fp32 streams summed then packed (query + query_pos)
// Round 3 verified the reg-staged write path is conflict-free and numerically
// identical; its perf failure was the missing XCD swizzle (now present).
#define TM 128
#define TN 96
#define BK 32

#define AM_BF16   0
#define AM_F32    1
#define AM_F32ADD 2

__device__ __forceinline__ void async_cp16(const ushort* gsrc, ushort* ldst) {
    __builtin_amdgcn_global_load_lds(
        (const __attribute__((address_space(1))) void*)gsrc,
        (__attribute__((address_space(3))) void*)ldst, 16, 0, 0);
}

// id in [0, total), total % 8 == 0. Returns (bx=M-block, by=N-block).
__device__ __forceinline__ void xcd_map(int id, int total, int nbn, int& bx, int& by) {
    const int xcd = id & 7;
    const int pos = id >> 3;
    const int logical = xcd * (total >> 3) + pos;
    by = logical % nbn;
    bx = logical / nbn;
}

template <int AMODE, typename OutT>
__device__ __forceinline__ void gemm_body(ushort* __restrict__ smem, int bx, int by,
                                          const void* __restrict__ Apv,
                                          const float* __restrict__ A2,
                                          const ushort* __restrict__ Bt,
                                          const float* __restrict__ bias,
                                          OutT* __restrict__ C, int K, int ldc) {
    ushort* Asb = smem;              // TM*BK, 8 chunks of [16][32]
    ushort* Bsb = smem + TM * BK;    // TN*BK, 6 chunks of [16][32]
    const int tid  = threadIdx.x;
    const int wave = tid >> 6;
    const int lane = tid & 63;
    const int m16  = lane & 15;
    const int quad = lane >> 4;
    const int wr   = wave >> 1;          // wave row 0..1 (64 rows each)
    const int wc   = wave & 1;           // wave col 0..1 (48 cols each)
    const int row0 = bx * TM;
    const int n0   = by * TN;

    const f32x4 zero = {0.f, 0.f, 0.f, 0.f};
    f32x4 acc[4][3];
    #pragma unroll
    for (int rt = 0; rt < 4; ++rt)
        #pragma unroll
        for (int ct = 0; ct < 3; ++ct) acc[rt][ct] = zero;

    const int srow = lane >> 2;                                  // 0..15
    const int scol = (((lane & 3) ^ ((lane >> 3) & 3))) * 8;     // inverse-swizzled src k-chunk
    const int ksw  = (quad ^ ((m16 >> 1) & 3)) * 8;              // swizzled read k-offset

    // reg-staged A geometry (f32 modes): thread owns row ((wave&1)<<6)|lane,
    // k-half wave>>1 (16 consecutive floats)
    const int srow_f = ((wave & 1) << 6) | lane;
    const int khalf  = wave >> 1;
    const float* A32  = (const float*)Apv;
    const ushort* A16 = (const ushort*)Apv;
    const float* arow  = A32 + (size_t)(row0 + srow_f) * K + khalf * 16;
    const float* arow2 = (AMODE == AM_F32ADD)
                         ? A2 + (size_t)(row0 + srow_f) * K + khalf * 16 : nullptr;

    for (int k0 = 0; k0 < K; k0 += BK) {
        float4 av0, av1, av2, av3, bv0, bv1, bv2, bv3;
        if constexpr (AMODE == AM_BF16) {
            #pragma unroll
            for (int c = 0; c < 2; ++c) {
                const int ch = wave + c * 4;
                async_cp16(A16 + (size_t)(row0 + ch * 16 + srow) * K + k0 + scol,
                           Asb + ch * 512 + lane * 8);
            }
        } else {
            av0 = *reinterpret_cast<const float4*>(arow + k0);
            av1 = *reinterpret_cast<const float4*>(arow + k0 + 4);
            av2 = *reinterpret_cast<const float4*>(arow + k0 + 8);
            av3 = *reinterpret_cast<const float4*>(arow + k0 + 12);
            if constexpr (AMODE == AM_F32ADD) {
                bv0 = *reinterpret_cast<const float4*>(arow2 + k0);
                bv1 = *reinterpret_cast<const float4*>(arow2 + k0 + 4);
                bv2 = *reinterpret_cast<const float4*>(arow2 + k0 + 8);
                bv3 = *reinterpret_cast<const float4*>(arow2 + k0 + 12);
            }
        }
        // B staging (always bf16 weights via global_load_lds) — flies under A wait
        async_cp16(Bt + (size_t)(n0 + wave * 16 + srow) * K + k0 + scol,
                   Bsb + wave * 512 + lane * 8);
        if (wave < 2)
            async_cp16(Bt + (size_t)(n0 + (wave + 4) * 16 + srow) * K + k0 + scol,
                       Bsb + (wave + 4) * 512 + lane * 8);

        if constexpr (AMODE != AM_BF16) {
            if constexpr (AMODE == AM_F32ADD) {
                av0.x += bv0.x; av0.y += bv0.y; av0.z += bv0.z; av0.w += bv0.w;
                av1.x += bv1.x; av1.y += bv1.y; av1.z += bv1.z; av1.w += bv1.w;
                av2.x += bv2.x; av2.y += bv2.y; av2.z += bv2.z; av2.w += bv2.w;
                av3.x += bv3.x; av3.y += bv3.y; av3.z += bv3.z; av3.w += bv3.w;
            }
            const int r  = srow_f & 15;
            const int ck = srow_f >> 4;
            const int xr = (r >> 1) & 3;
            const int s0 = khalf * 2;
            u32x4 w0 = {(uint32_t)f2b(av0.x) | ((uint32_t)f2b(av0.y) << 16),
                        (uint32_t)f2b(av0.z) | ((uint32_t)f2b(av0.w) << 16),
                        (uint32_t)f2b(av1.x) | ((uint32_t)f2b(av1.y) << 16),
                        (uint32_t)f2b(av1.z) | ((uint32_t)f2b(av1.w) << 16)};
            u32x4 w1 = {(uint32_t)f2b(av2.x) | ((uint32_t)f2b(av2.y) << 16),
                        (uint32_t)f2b(av2.z) | ((uint32_t)f2b(av2.w) << 16),
                        (uint32_t)f2b(av3.x) | ((uint32_t)f2b(av3.y) << 16),
                        (uint32_t)f2b(av3.z) | ((uint32_t)f2b(av3.w) << 16)};
            *reinterpret_cast<u32x4*>(&Asb[ck * 512 + r * 32 + ((s0 ^ xr) * 8)]) = w0;
            *reinterpret_cast<u32x4*>(&Asb[ck * 512 + r * 32 + (((s0 + 1) ^ xr) * 8)]) = w1;
        }
        __syncthreads();

        short8 afrag[4], bfrag[3];
        #pragma unroll
        for (int rt = 0; rt < 4; ++rt)
            afrag[rt] = *reinterpret_cast<const short8*>(
                Asb + (wr * 4 + rt) * 512 + m16 * 32 + ksw);
        #pragma unroll
        for (int ct = 0; ct < 3; ++ct)
            bfrag[ct] = *reinterpret_cast<const short8*>(
                Bsb + (wc * 3 + ct) * 512 + m16 * 32 + ksw);

        #pragma unroll
        for (int rt = 0; rt < 4; ++rt)
            #pragma unroll
            for (int ct = 0; ct < 3; ++ct)
                acc[rt][ct] = __builtin_amdgcn_mfma_f32_16x16x32_bf16(
                    afrag[rt], bfrag[ct], acc[rt][ct], 0, 0, 0);

        __syncthreads();
    }

    #pragma unroll
    for (int ct = 0; ct < 3; ++ct) {
        const int col = n0 + wc * 48 + ct * 16 + m16;
        const float bcol = bias[col];
        #pragma unroll
        for (int rt = 0; rt < 4; ++rt) {
            #pragma unroll
            for (int r = 0; r < 4; ++r) {
                const int row = row0 + wr * 64 + rt * 16 + quad * 4 + r;
                const float val = acc[rt][ct][r] + bcol;
                if constexpr (__is_same(OutT, float)) {
                    C[(size_t)row * ldc + col] = val;
                } else {
                    C[(size_t)row * ldc + col] = f2b(val);
                }
            }
        }
    }
}

// standalone GEMM (out projection): 480 blocks = 80 M x 6 N, XCD-chunked
__global__ void gemm_out(const ushort* __restrict__ A, const ushort* __restrict__ Bt,
                         const float* __restrict__ bias, float* __restrict__ C,
                         int K, int ldc, int total, int nbn) {
    __shared__ __align__(16) ushort smem[(TM + TN) * BK];
    int bx, by;
    xcd_map(blockIdx.x, total, nbn, bx, by);
    gemm_body<AM_BF16, float>(smem, bx, by, A, nullptr, Bt, bias, C, K, ldc);
}

// two independent GEMMs in one launch, fused fp32 casts in A-staging:
//   GEMM1 (mix):   A = query + query_pos (fp32+fp32), fp32 out
//   GEMM2 (value): A = value (fp32), bf16 out
__global__ void gemm_dual(const float* __restrict__ q, const float* __restrict__ qp,
                          const ushort* __restrict__ B1,
                          const float* __restrict__ bias1, float* __restrict__ C1,
                          int K1, int ldc1, int nbn1, int split,
                          const float* __restrict__ val, const ushort* __restrict__ B2,
                          const float* __restrict__ bias2, ushort* __restrict__ C2,
                          int K2, int ldc2, int nbn2, int total2) {
    __shared__ __align__(16) ushort smem[(TM + TN) * BK];
    const int id = blockIdx.x;
    int bx, by;
    if (id < split) {
        xcd_map(id, split, nbn1, bx, by);
        gemm_body<AM_F32ADD, float>(smem, bx, by, q, qp, B1, bias1, C1, K1, ldc1);
    } else {
        xcd_map(id - split, total2, nbn2, bx, by);
        gemm_body<AM_F32, ushort>(smem, bx, by, val, nullptr, B2, bias2, C2, K2, ldc2);
    }
}

// ---------------------------------------------------------------------------
// Deformable 3D trilinear attention — compacted-corner LDS version, head-major.
// (unchanged from round 5 — contributed ~-25 us there)
__global__ void __launch_bounds__(256, 8)
deform_kernel(const ushort* __restrict__ vbuf,
              const float* __restrict__ mix,
              ushort* __restrict__ aout) {
    __shared__ uint2 corn[16 * 97];      // 97-pair stride: subgroup bases on distinct banks
    __shared__ int   ccnt[16];
    const int gl   = threadIdx.x >> 4;   // subgroup in block
    const int l    = threadIdx.x & 15;
    const int head = blockIdx.x / 640;                   // block-uniform
    const int bq   = (blockIdx.x % 640) * 16 + gl;       // b*NQ + q
    const int q    = bq % NQ;
    const int b    = bq / NQ;
    const int qx   = q % GW;
    const int qy   = q / GW;

    const float* mrow = mix + (size_t)bq * MIXW;

    // --- phase 1: softmax (lanes 0..11 hold one logit each) ---
    float lg = (l < NPTS) ? mrow[648 + head * NPTS + l] : -1e30f;
    float mx = lg;
    #pragma unroll
    for (int mk = 1; mk < 16; mk <<= 1) mx = fmaxf(mx, __shfl_xor(mx, mk, 16));
    float e = (l < NPTS) ? __expf(lg - mx) : 0.f;
    float s = e;
    #pragma unroll
    for (int mk = 1; mk < 16; mk <<= 1) s += __shfl_xor(s, mk, 16);

    // --- phase 1b: corner geometry for point l (lanes 0..11) ---
    float    cw[8];
    uint32_t coff[8];
    uint32_t mask = 0;
    {
        const float ap = e / s;
        const int pl = (l < NPTS) ? l : 0;
        const int ob = (head * NPTS + pl) * 3;
        const float ox = mrow[ob + 0];
        const float oy = mrow[ob + 1];
        const float oz = mrow[ob + 2];
        const float x = (float)qx + ox;          // = loc_x*W - 0.5
        const float y = (float)qy + oy;
        const float z = oz * (5.0f / 3.0f) - 0.5f;
        const float x0f = floorf(x), y0f = floorf(y), z0f = floorf(z);
        const int x0 = (int)x0f, y0 = (int)y0f, z0 = (int)z0f;
        const float fx = x - x0f, fy = y - y0f, fz = z - z0f;

        #pragma unroll
        for (int dz = 0; dz < 2; ++dz) {
            const int zi = z0 + dz;
            const bool zv = (zi >= 0) & (zi < DDEPTH);
            const int zc = min(max(zi, 0), DDEPTH - 1);
            const float wz = dz ? fz : 1.f - fz;
            #pragma unroll
            for (int dy = 0; dy < 2; ++dy) {
                const int yi = y0 + dy;
                const bool yv = (yi >= 0) & (yi < GH);
                const int yc = min(max(yi, 0), GH - 1);
                const float wy = dy ? fy : 1.f - fy;
                #pragma unroll
                for (int dx = 0; dx < 2; ++dx) {
                    const int xi = x0 + dx;
                    const bool xv = (xi >= 0) & (xi < GW);
                    const int xc = min(max(xi, 0), GW - 1);
                    const float wx = dx ? fx : 1.f - fx;
                    const int i = dz * 4 + dy * 2 + dx;
                    const bool valid = zv & yv & xv & (l < NPTS);
                    cw[i]   = ap * wz * wy * wx;
                    coff[i] = (uint32_t)((zc * GH + yc) * GW + xc) * (E_DIM / 2);
                    mask |= (valid ? (1u << i) : 0u);
                }
            }
        }
    }

    // --- compaction: prefix-sum valid counts across the 16 lanes ---
    const int cnt = __popc(mask);
    int pre = cnt;                        // inclusive prefix
    #pragma unroll
    for (int mk = 1; mk < 16; mk <<= 1) {
        const int t = __shfl_up(pre, mk, 16);
        if (l >= mk) pre += t;
    }
    int o = gl * 97 + (pre - cnt);        // exclusive base for this point
    #pragma unroll
    for (int i = 0; i < 8; ++i) {
        if (mask & (1u << i)) {
            uint2 w; w.x = __float_as_uint(cw[i]); w.y = coff[i];
            corn[o] = w;
            ++o;
        }
    }
    if (l == 15) ccnt[gl] = pre;          // lane 15 inclusive = total valid
    __syncthreads();

    // --- phase 2: branch-free gather (all 16 lanes; lane = channel pair) ---
    const uint32_t lbase = (uint32_t)b * (uint32_t)(NTOK * (E_DIM / 2))
                         + (uint32_t)(head * (HDIM / 2) + l);
    const uint32_t* vb32 = reinterpret_cast<const uint32_t*>(vbuf);
    const int n = ccnt[gl];
    const uint2* cg = &corn[gl * 97];
    float o0 = 0.f, o1 = 0.f;
    #pragma unroll 2
    for (int j = 0; j < n; ++j) {
        const uint2 wo = cg[j];                 // uniform addr -> broadcast
        const uint32_t pair = vb32[lbase + wo.y];
        const float w = __uint_as_float(wo.x);
        o0 += w * b2f_lo(pair);
        o1 += w * b2f_hi(pair);
    }
    const uint32_t packed = (uint32_t)f2b(o0) | ((uint32_t)f2b(o1) << 16);
    reinterpret_cast<uint32_t*>(aout)[(size_t)bq * (E_DIM / 2) + head * (HDIM / 2) + l] = packed;
}

// ---------------------------------------------------------------------------
extern "C" void kernel_launch(void* const* d_in, const int* in_sizes, int n_in,
                              void* d_out, int out_size, void* d_ws, size_t ws_size,
                              hipStream_t stream) {
    const float* query     = (const float*)d_in[0];
    const float* value     = (const float*)d_in[1];
    const float* query_pos = (const float*)d_in[2];
    const float* W_off     = (const float*)d_in[3];
    const float* b_off     = (const float*)d_in[4];
    const float* W_attn    = (const float*)d_in[5];
    const float* b_attn    = (const float*)d_in[6];
    const float* W_v       = (const float*)d_in[7];
    const float* b_v       = (const float*)d_in[8];
    const float* W_out     = (const float*)d_in[9];
    const float* b_out     = (const float*)d_in[10];
    float* out = (float*)d_out;

    char* ws = (char*)d_ws;
    ushort* vbuf     = (ushort*)(ws);                  // 58,982,400
    ushort* aout     = (ushort*)(ws + 58982400);       // 11,796,480
    float*  mixb     = (float*) (ws + 70778880);       // 35,389,440
    ushort* wt_v     = (ushort*)(ws + 106168320);      // 663,552
    ushort* wt_out   = (ushort*)(ws + 106831872);      // 663,552
    ushort* wt_mix   = (ushort*)(ws + 107495424);      // 995,328
    float*  bias_mix = (float*) (ws + 108490752);      // 3,456

    // weight prep only (~2.7 MB)
    prep_weights<<<(1161216 + 255) / 256, 256, 0, stream>>>(
        W_v, W_out, W_off, W_attn, b_off, b_attn, wt_v, wt_out, wt_mix, bias_mix);

    // mix GEMM (10240x864, A = query+query_pos fp32, fp32 out, 80Mx9N=720) +
    // value GEMM (51200x576, A = value fp32, bf16 out, 400Mx6N=2400),
    // both with fused cast in A-staging and XCD-chunked N-fastest block map.
    gemm_dual<<<720 + 2400, 256, 0, stream>>>(
        query, query_pos, wt_mix, bias_mix, mixb, E_DIM, MIXW, 9, 720,
        value, wt_v, b_v, vbuf, E_DIM, E_DIM, 6, 2400);

    // deformable gather + softmax-weighted sum -> aout (bf16), head-major grid
    deform_kernel<<<HEADS * 640, 256, 0, stream>>>(vbuf, mixb, aout);

    // out = aout @ W_out + b_out : (10240 x 576), fp32 to d_out
    gemm_out<<<480, 256, 0, stream>>>(
        aout, wt_out, b_out, out, E_DIM, E_DIM, 480, 6);
}

// Round 8
// 432.018 us; speedup vs baseline: 1.0034x; 1.0034x over previous
//
#include <hip/hip_runtime.h>
#include <cstdint>

// Problem constants (fixed shapes)
#define E_DIM   576
#define HEADS   18
#define NPTS    12
#define DDEPTH  5
#define HDIM    32
#define BSZ     2
#define GH      64
#define GW      80
#define NQ      (GH*GW)       // 5120
#define NTOK    (NQ*DDEPTH)   // 25600
#define MIXW    864           // 648 offsets + 216 attn logits
#define BQ_TOT  (BSZ*NQ)      // 10240

typedef __attribute__((ext_vector_type(8))) short short8;
typedef __attribute__((ext_vector_type(4))) float f32x4;
typedef __attribute__((ext_vector_type(4))) uint32_t u32x4;

__device__ __forceinline__ float b2f_lo(uint32_t u) {
    union { uint32_t u; float f; } v; v.u = u << 16; return v.f;
}
__device__ __forceinline__ float b2f_hi(uint32_t u) {
    union { uint32_t u; float f; } v; v.u = u & 0xffff0000u; return v.f;
}
__device__ __forceinline__ ushort f2b(float f) {
    union { float f; uint32_t u; } v; v.f = f;
    return (ushort)((v.u + 0x7fffu + ((v.u >> 16) & 1u)) >> 16);
}

// ---------------------------------------------------------------------------
// Weight prep only: weight transposes + bias concat, ~2.7 MB total.
__global__ void prep_weights(const float* __restrict__ W_v, const float* __restrict__ W_out,
                             const float* __restrict__ W_off, const float* __restrict__ W_attn,
                             const float* __restrict__ b_off, const float* __restrict__ b_attn,
                             ushort* __restrict__ wt_v, ushort* __restrict__ wt_out,
                             ushort* __restrict__ wt_mix, float* __restrict__ bias_mix) {
    int idx = blockIdx.x * blockDim.x + threadIdx.x;
    if (idx < 864) bias_mix[idx] = (idx < 648) ? b_off[idx] : b_attn[idx - 648];
    if (idx < 331776) {
        int n = idx / E_DIM, k = idx - n * E_DIM;
        wt_v[idx] = f2b(W_v[(size_t)k * E_DIM + n]);
    } else if (idx < 663552) {
        int j = idx - 331776;
        int n = j / E_DIM, k = j - n * E_DIM;
        wt_out[j] = f2b(W_out[(size_t)k * E_DIM + n]);
    } else if (idx < 1161216) {
        int j = idx - 663552;
        int n = j / E_DIM, k = j - n * E_DIM;
        float v = (n < 648) ? W_off[(size_t)k * 648 + n] : W_attn[(size_t)k * 216 + (n - 648)];
        wt_mix[j] = f2b(v);
    }
}

// ---------------------------------------------------------------------------
// MFMA GEMM body: C[M,N] = A[M,K] @ Bt[N,K]^T + bias[N]
// Tile 128x96, BK=32, 256 threads = 4 waves in a 2x2 grid (each wave 64x48).
// XOR k-slot swizzle (phys_slot = logical ^ ((row>>1)&3)): bank conflicts 0.
// XCD-chunked block map: panel sharers colocated on one XCD's L2
// (round 5: FETCH 164->44 MB, -14 us).
//
// A-operand modes:
//   AM_BF16  : A bf16, single-buffered global_load_lds (round-1 proven, 68us)
//   AM_F32   : A fp32, fused cast, DOUBLE-buffered issue-early/write-late
//   AM_F32ADD: query+query_pos fused add+cast, same dbuf schedule
// Lesson of rounds 3 vs 6: fused reg-staged A needs BOTH the XCD map (traffic,
// r3 failed without it: 352MB) AND the dbuf issue-early/write-late schedule
// (latency, r6 failed without it: 210us). This round has both.
#define TM 128
#define TN 96
#define BK 32

#define AM_BF16   0
#define AM_F32    1
#define AM_F32ADD 2

__device__ __forceinline__ void async_cp16(const ushort* gsrc, ushort* ldst) {
    __builtin_amdgcn_global_load_lds(
        (const __attribute__((address_space(1))) void*)gsrc,
        (__attribute__((address_space(3))) void*)ldst, 16, 0, 0);
}

// id in [0, total), total % 8 == 0. Returns (bx=M-block, by=N-block).
__device__ __forceinline__ void xcd_map(int id, int total, int nbn, int& bx, int& by) {
    const int xcd = id & 7;
    const int pos = id >> 3;
    const int logical = xcd * (total >> 3) + pos;
    by = logical % nbn;
    bx = logical / nbn;
}

template <int AMODE, typename OutT>
__device__ __forceinline__ void gemm_body(ushort* __restrict__ smem, int bx, int by,
                                          const void* __restrict__ Apv,
                                          const float* __restrict__ A2,
                                          const ushort* __restrict__ Bt,
                                          const float* __restrict__ bias,
                                          OutT* __restrict__ C, int K, int ldc) {
    const int tid  = threadIdx.x;
    const int wave = tid >> 6;
    const int lane = tid & 63;
    const int m16  = lane & 15;
    const int quad = lane >> 4;
    const int wr   = wave >> 1;          // wave row 0..1 (64 rows each)
    const int wc   = wave & 1;           // wave col 0..1 (48 cols each)
    const int row0 = bx * TM;
    const int n0   = by * TN;

    const f32x4 zero = {0.f, 0.f, 0.f, 0.f};
    f32x4 acc[4][3];
    #pragma unroll
    for (int rt = 0; rt < 4; ++rt)
        #pragma unroll
        for (int ct = 0; ct < 3; ++ct) acc[rt][ct] = zero;

    const int srow = lane >> 2;                                  // 0..15
    const int scol = (((lane & 3) ^ ((lane >> 3) & 3))) * 8;     // inverse-swizzled src k-chunk
    const int ksw  = (quad ^ ((m16 >> 1) & 3)) * 8;              // swizzled read k-offset

    auto readfrag_mfma = [&](ushort* Asb, ushort* Bsb) {
        short8 afrag[4], bfrag[3];
        #pragma unroll
        for (int rt = 0; rt < 4; ++rt)
            afrag[rt] = *reinterpret_cast<const short8*>(
                Asb + (wr * 4 + rt) * 512 + m16 * 32 + ksw);
        #pragma unroll
        for (int ct = 0; ct < 3; ++ct)
            bfrag[ct] = *reinterpret_cast<const short8*>(
                Bsb + (wc * 3 + ct) * 512 + m16 * 32 + ksw);
        #pragma unroll
        for (int rt = 0; rt < 4; ++rt)
            #pragma unroll
            for (int ct = 0; ct < 3; ++ct)
                acc[rt][ct] = __builtin_amdgcn_mfma_f32_16x16x32_bf16(
                    afrag[rt], bfrag[ct], acc[rt][ct], 0, 0, 0);
    };
    auto stageB = [&](ushort* Bsb, int k0) {
        async_cp16(Bt + (size_t)(n0 + wave * 16 + srow) * K + k0 + scol,
                   Bsb + wave * 512 + lane * 8);
        if (wave < 2)
            async_cp16(Bt + (size_t)(n0 + (wave + 4) * 16 + srow) * K + k0 + scol,
                       Bsb + (wave + 4) * 512 + lane * 8);
    };

    if constexpr (AMODE == AM_BF16) {
        // single-buffered global_load_lds path (round-1 proven)
        ushort* Asb = smem;
        ushort* Bsb = smem + TM * BK;
        const ushort* A16 = (const ushort*)Apv;
        for (int k0 = 0; k0 < K; k0 += BK) {
            #pragma unroll
            for (int c = 0; c < 2; ++c) {
                const int ch = wave + c * 4;
                async_cp16(A16 + (size_t)(row0 + ch * 16 + srow) * K + k0 + scol,
                           Asb + ch * 512 + lane * 8);
            }
            stageB(Bsb, k0);
            __syncthreads();
            readfrag_mfma(Asb, Bsb);
            __syncthreads();
        }
    } else {
        // double-buffered fused-cast path: issue-early / write-late (T14)
        ushort* Asb0 = smem;
        ushort* Bsb0 = smem + TM * BK;
        ushort* Asb1 = smem + (TM + TN) * BK;
        ushort* Bsb1 = Asb1 + TM * BK;

        const int srow_f = ((wave & 1) << 6) | lane;   // row 0..127
        const int khalf  = wave >> 1;                  // 16-float half
        const float* arow  = (const float*)Apv + (size_t)(row0 + srow_f) * K + khalf * 16;
        const float* arow2 = (AMODE == AM_F32ADD)
                             ? A2 + (size_t)(row0 + srow_f) * K + khalf * 16 : nullptr;

        float4 av0, av1, av2, av3, bv0, bv1, bv2, bv3;
        auto issueA = [&](int k0) {
            av0 = *reinterpret_cast<const float4*>(arow + k0);
            av1 = *reinterpret_cast<const float4*>(arow + k0 + 4);
            av2 = *reinterpret_cast<const float4*>(arow + k0 + 8);
            av3 = *reinterpret_cast<const float4*>(arow + k0 + 12);
            if constexpr (AMODE == AM_F32ADD) {
                bv0 = *reinterpret_cast<const float4*>(arow2 + k0);
                bv1 = *reinterpret_cast<const float4*>(arow2 + k0 + 4);
                bv2 = *reinterpret_cast<const float4*>(arow2 + k0 + 8);
                bv3 = *reinterpret_cast<const float4*>(arow2 + k0 + 12);
            }
        };
        auto writeA = [&](ushort* Asb) {
            if constexpr (AMODE == AM_F32ADD) {
                av0.x += bv0.x; av0.y += bv0.y; av0.z += bv0.z; av0.w += bv0.w;
                av1.x += bv1.x; av1.y += bv1.y; av1.z += bv1.z; av1.w += bv1.w;
                av2.x += bv2.x; av2.y += bv2.y; av2.z += bv2.z; av2.w += bv2.w;
                av3.x += bv3.x; av3.y += bv3.y; av3.z += bv3.z; av3.w += bv3.w;
            }
            const int r  = srow_f & 15;
            const int ck = srow_f >> 4;
            const int xr = (r >> 1) & 3;
            const int s0 = khalf * 2;
            u32x4 w0 = {(uint32_t)f2b(av0.x) | ((uint32_t)f2b(av0.y) << 16),
                        (uint32_t)f2b(av0.z) | ((uint32_t)f2b(av0.w) << 16),
                        (uint32_t)f2b(av1.x) | ((uint32_t)f2b(av1.y) << 16),
                        (uint32_t)f2b(av1.z) | ((uint32_t)f2b(av1.w) << 16)};
            u32x4 w1 = {(uint32_t)f2b(av2.x) | ((uint32_t)f2b(av2.y) << 16),
                        (uint32_t)f2b(av2.z) | ((uint32_t)f2b(av2.w) << 16),
                        (uint32_t)f2b(av3.x) | ((uint32_t)f2b(av3.y) << 16),
                        (uint32_t)f2b(av3.z) | ((uint32_t)f2b(av3.w) << 16)};
            *reinterpret_cast<u32x4*>(&Asb[ck * 512 + r * 32 + ((s0 ^ xr) * 8)]) = w0;
            *reinterpret_cast<u32x4*>(&Asb[ck * 512 + r * 32 + (((s0 + 1) ^ xr) * 8)]) = w1;
        };

        // prologue: stage tile 0 into buf0
        issueA(0);
        stageB(Bsb0, 0);
        writeA(Asb0);
        __syncthreads();

        int cur = 0;
        for (int k0 = 0; k0 < K; k0 += BK) {
            ushort* Acur = cur ? Asb1 : Asb0;
            ushort* Bcur = cur ? Bsb1 : Bsb0;
            ushort* Anxt = cur ? Asb0 : Asb1;
            ushort* Bnxt = cur ? Bsb0 : Bsb1;
            const bool nx = (k0 + BK < K);
            if (nx) {
                issueA(k0 + BK);       // reg loads in flight under MFMA
                stageB(Bnxt, k0 + BK); // async B loads in flight under MFMA
            }
            readfrag_mfma(Acur, Bcur);
            if (nx) writeA(Anxt);      // cvt+ds_write after compute covered latency
            __syncthreads();
            cur ^= 1;
        }
    }

    #pragma unroll
    for (int ct = 0; ct < 3; ++ct) {
        const int col = n0 + wc * 48 + ct * 16 + m16;
        const float bcol = bias[col];
        #pragma unroll
        for (int rt = 0; rt < 4; ++rt) {
            #pragma unroll
            for (int r = 0; r < 4; ++r) {
                const int row = row0 + wr * 64 + rt * 16 + quad * 4 + r;
                const float val = acc[rt][ct][r] + bcol;
                if constexpr (__is_same(OutT, float)) {
                    C[(size_t)row * ldc + col] = val;
                } else {
                    C[(size_t)row * ldc + col] = f2b(val);
                }
            }
        }
    }
}

// standalone GEMM (out projection): 480 blocks = 80 M x 6 N, XCD-chunked
__global__ void gemm_out(const ushort* __restrict__ A, const ushort* __restrict__ Bt,
                         const float* __restrict__ bias, float* __restrict__ C,
                         int K, int ldc, int total, int nbn) {
    __shared__ __align__(16) ushort smem[(TM + TN) * BK];
    int bx, by;
    xcd_map(blockIdx.x, total, nbn, bx, by);
    gemm_body<AM_BF16, float>(smem, bx, by, A, nullptr, Bt, bias, C, K, ldc);
}

// two independent GEMMs in one launch, fused fp32 casts in A-staging (dbuf):
//   GEMM1 (mix):   A = query + query_pos (fp32+fp32), fp32 out
//   GEMM2 (value): A = value (fp32), bf16 out
__global__ void gemm_dual(const float* __restrict__ q, const float* __restrict__ qp,
                          const ushort* __restrict__ B1,
                          const float* __restrict__ bias1, float* __restrict__ C1,
                          int K1, int ldc1, int nbn1, int split,
                          const float* __restrict__ val, const ushort* __restrict__ B2,
                          const float* __restrict__ bias2, ushort* __restrict__ C2,
                          int K2, int ldc2, int nbn2, int total2) {
    __shared__ __align__(16) ushort smem[2 * (TM + TN) * BK];
    const int id = blockIdx.x;
    int bx, by;
    if (id < split) {
        xcd_map(id, split, nbn1, bx, by);
        gemm_body<AM_F32ADD, float>(smem, bx, by, q, qp, B1, bias1, C1, K1, ldc1);
    } else {
        xcd_map(id - split, total2, nbn2, bx, by);
        gemm_body<AM_F32, ushort>(smem, bx, by, val, nullptr, B2, bias2, C2, K2, ldc2);
    }
}

// ---------------------------------------------------------------------------
// Deformable 3D trilinear attention — compacted-corner LDS version, head-major.
// (unchanged from round 5)
__global__ void __launch_bounds__(256, 8)
deform_kernel(const ushort* __restrict__ vbuf,
              const float* __restrict__ mix,
              ushort* __restrict__ aout) {
    __shared__ uint2 corn[16 * 97];      // 97-pair stride: subgroup bases on distinct banks
    __shared__ int   ccnt[16];
    const int gl   = threadIdx.x >> 4;   // subgroup in block
    const int l    = threadIdx.x & 15;
    const int head = blockIdx.x / 640;                   // block-uniform
    const int bq   = (blockIdx.x % 640) * 16 + gl;       // b*NQ + q
    const int q    = bq % NQ;
    const int b    = bq / NQ;
    const int qx   = q % GW;
    const int qy   = q / GW;

    const float* mrow = mix + (size_t)bq * MIXW;

    // --- phase 1: softmax (lanes 0..11 hold one logit each) ---
    float lg = (l < NPTS) ? mrow[648 + head * NPTS + l] : -1e30f;
    float mx = lg;
    #pragma unroll
    for (int mk = 1; mk < 16; mk <<= 1) mx = fmaxf(mx, __shfl_xor(mx, mk, 16));
    float e = (l < NPTS) ? __expf(lg - mx) : 0.f;
    float s = e;
    #pragma unroll
    for (int mk = 1; mk < 16; mk <<= 1) s += __shfl_xor(s, mk, 16);

    // --- phase 1b: corner geometry for point l (lanes 0..11) ---
    float    cw[8];
    uint32_t coff[8];
    uint32_t mask = 0;
    {
        const float ap = e / s;
        const int pl = (l < NPTS) ? l : 0;
        const int ob = (head * NPTS + pl) * 3;
        const float ox = mrow[ob + 0];
        const float oy = mrow[ob + 1];
        const float oz = mrow[ob + 2];
        const float x = (float)qx + ox;          // = loc_x*W - 0.5
        const float y = (float)qy + oy;
        const float z = oz * (5.0f / 3.0f) - 0.5f;
        const float x0f = floorf(x), y0f = floorf(y), z0f = floorf(z);
        const int x0 = (int)x0f, y0 = (int)y0f, z0 = (int)z0f;
        const float fx = x - x0f, fy = y - y0f, fz = z - z0f;

        #pragma unroll
        for (int dz = 0; dz < 2; ++dz) {
            const int zi = z0 + dz;
            const bool zv = (zi >= 0) & (zi < DDEPTH);
            const int zc = min(max(zi, 0), DDEPTH - 1);
            const float wz = dz ? fz : 1.f - fz;
            #pragma unroll
            for (int dy = 0; dy < 2; ++dy) {
                const int yi = y0 + dy;
                const bool yv = (yi >= 0) & (yi < GH);
                const int yc = min(max(yi, 0), GH - 1);
                const float wy = dy ? fy : 1.f - fy;
                #pragma unroll
                for (int dx = 0; dx < 2; ++dx) {
                    const int xi = x0 + dx;
                    const bool xv = (xi >= 0) & (xi < GW);
                    const int xc = min(max(xi, 0), GW - 1);
                    const float wx = dx ? fx : 1.f - fx;
                    const int i = dz * 4 + dy * 2 + dx;
                    const bool valid = zv & yv & xv & (l < NPTS);
                    cw[i]   = ap * wz * wy * wx;
                    coff[i] = (uint32_t)((zc * GH + yc) * GW + xc) * (E_DIM / 2);
                    mask |= (valid ? (1u << i) : 0u);
                }
            }
        }
    }

    // --- compaction: prefix-sum valid counts across the 16 lanes ---
    const int cnt = __popc(mask);
    int pre = cnt;                        // inclusive prefix
    #pragma unroll
    for (int mk = 1; mk < 16; mk <<= 1) {
        const int t = __shfl_up(pre, mk, 16);
        if (l >= mk) pre += t;
    }
    int o = gl * 97 + (pre - cnt);        // exclusive base for this point
    #pragma unroll
    for (int i = 0; i < 8; ++i) {
        if (mask & (1u << i)) {
            uint2 w; w.x = __float_as_uint(cw[i]); w.y = coff[i];
            corn[o] = w;
            ++o;
        }
    }
    if (l == 15) ccnt[gl] = pre;          // lane 15 inclusive = total valid
    __syncthreads();

    // --- phase 2: branch-free gather (all 16 lanes; lane = channel pair) ---
    const uint32_t lbase = (uint32_t)b * (uint32_t)(NTOK * (E_DIM / 2))
                         + (uint32_t)(head * (HDIM / 2) + l);
    const uint32_t* vb32 = reinterpret_cast<const uint32_t*>(vbuf);
    const int n = ccnt[gl];
    const uint2* cg = &corn[gl * 97];
    float o0 = 0.f, o1 = 0.f;
    #pragma unroll 2
    for (int j = 0; j < n; ++j) {
        const uint2 wo = cg[j];                 // uniform addr -> broadcast
        const uint32_t pair = vb32[lbase + wo.y];
        const float w = __uint_as_float(wo.x);
        o0 += w * b2f_lo(pair);
        o1 += w * b2f_hi(pair);
    }
    const uint32_t packed = (uint32_t)f2b(o0) | ((uint32_t)f2b(o1) << 16);
    reinterpret_cast<uint32_t*>(aout)[(size_t)bq * (E_DIM / 2) + head * (HDIM / 2) + l] = packed;
}

// ---------------------------------------------------------------------------
extern "C" void kernel_launch(void* const* d_in, const int* in_sizes, int n_in,
                              void* d_out, int out_size, void* d_ws, size_t ws_size,
                              hipStream_t stream) {
    const float* query     = (const float*)d_in[0];
    const float* value     = (const float*)d_in[1];
    const float* query_pos = (const float*)d_in[2];
    const float* W_off     = (const float*)d_in[3];
    const float* b_off     = (const float*)d_in[4];
    const float* W_attn    = (const float*)d_in[5];
    const float* b_attn    = (const float*)d_in[6];
    const float* W_v       = (const float*)d_in[7];
    const float* b_v       = (const float*)d_in[8];
    const float* W_out     = (const float*)d_in[9];
    const float* b_out     = (const float*)d_in[10];
    float* out = (float*)d_out;

    char* ws = (char*)d_ws;
    ushort* vbuf     = (ushort*)(ws);                  // 58,982,400
    ushort* aout     = (ushort*)(ws + 58982400);       // 11,796,480
    float*  mixb     = (float*) (ws + 70778880);       // 35,389,440
    ushort* wt_v     = (ushort*)(ws + 106168320);      // 663,552
    ushort* wt_out   = (ushort*)(ws + 106831872);      // 663,552
    ushort* wt_mix   = (ushort*)(ws + 107495424);      // 995,328
    float*  bias_mix = (float*) (ws + 108490752);      // 3,456

    // weight prep only (~2.7 MB)
    prep_weights<<<(1161216 + 255) / 256, 256, 0, stream>>>(
        W_v, W_out, W_off, W_attn, b_off, b_attn, wt_v, wt_out, wt_mix, bias_mix);

    // mix GEMM (10240x864, A = query+query_pos fp32, fp32 out, 80Mx9N=720) +
    // value GEMM (51200x576, A = value fp32, bf16 out, 400Mx6N=2400),
    // fused cast in dbuf A-staging + XCD-chunked N-fastest block map.
    gemm_dual<<<720 + 2400, 256, 0, stream>>>(
        query, query_pos, wt_mix, bias_mix, mixb, E_DIM, MIXW, 9, 720,
        value, wt_v, b_v, vbuf, E_DIM, E_DIM, 6, 2400);

    // deformable gather + softmax-weighted sum -> aout (bf16), head-major grid
    deform_kernel<<<HEADS * 640, 256, 0, stream>>>(vbuf, mixb, aout);

    // out = aout @ W_out + b_out : (10240 x 576), fp32 to d_out
    gemm_out<<<480, 256, 0, stream>>>(
        aout, wt_out, b_out, out, E_DIM, E_DIM, 480, 6);
}